// Round 7
// baseline (3709.753 us; speedup 1.0000x reference)
//
#include <hip/hip_runtime.h>
#include <stdint.h>

#define T_STEPS 512
#define RING 16
#define SLOT_SHORTS (64 * 1024)   // one h slot: 64x1024 bf16 = 128 KB

typedef short short8 __attribute__((ext_vector_type(8)));
typedef float f32x16 __attribute__((ext_vector_type(16)));

// ---- ws layout (bytes) ----
// done: [512][2 groups][4 pair-lines] x 64B; pair-line k = u64 {cnt[2k],cnt[2k+1]},
// counting WAVES: 16 blocks x 4 waves = 64 per cohort.
#define OFF_DONE 0
#define DONE_BYTES (512 * 2 * 4 * 64)               // 256 KB
#define OFF_HRING DONE_BYTES                        // 16 slots x 128 KB = 2 MB
#define OFF_WPACK (OFF_HRING + RING * SLOT_SHORTS * 2)
#define MEMSET_BYTES (OFF_HRING + SLOT_SHORTS * 2)  // counters + ring slot 0 (h_{-1}=0)

// LDS strides
#define W_STR 1544   // shorts = 772 dw
#define G_STR 36     // floats

__device__ __forceinline__ unsigned short f2bf(float f) {
  unsigned u = __float_as_uint(f);
  u += 0x7fffu + ((u >> 16) & 1u);   // RNE
  return (unsigned short)(u >> 16);
}

// ---- prep: W [k][col] f32 -> wp [colpack][k] bf16 ----
// col = g*1024 + u  ->  cp = (u>>3)*32 + g*8 + (u&7)  (block cb owns cp rows cb*32..+31)
__global__ __launch_bounds__(256) void k_wpack(const float* __restrict__ Wx,
                                               const float* __restrict__ Wh,
                                               unsigned short* __restrict__ wp) {
  __shared__ unsigned short tile[64 * 68];
  int tid = threadIdx.x, lane = tid & 63, wave = tid >> 6;
  int kt = blockIdx.x >> 6;   // 0..23
  int ct = blockIdx.x & 63;   // 0..63
  int K0 = kt * 64, C0 = ct * 64;
  const float* src = (K0 < 512) ? (Wx + (size_t)K0 * 4096)
                                : (Wh + (size_t)(K0 - 512) * 4096);
  #pragma unroll
  for (int i = 0; i < 16; ++i) {
    int kl = i * 4 + wave;
    float v = src[(size_t)kl * 4096 + C0 + lane];
    tile[lane * 68 + kl] = f2bf(v);
  }
  __syncthreads();
  #pragma unroll
  for (int i = 0; i < 16; ++i) {
    int c = i * 4 + wave;
    int col = C0 + c;
    int gg = col >> 10, idx = col & 1023;
    int cp = (idx >> 3) * 32 + gg * 8 + (idx & 7);
    wp[(size_t)cp * 1536 + K0 + lane] = tile[c * 68 + lane];
  }
}

// ---- persistent scan ----
// 256 blocks x 256 threads. g = bid&1 (32 batch rows), cb = bid>>1 (8 units = 32 cols).
// Wave = K-slice ks: X K [ks*128,+128), H K [ks*256,+256). 32x32x16 MFMA.
// Per-WAVE signaling: wave stores its own 8 h-rows (agent-scope u64 atomics -> LLC),
// s_waitcnt vmcnt(0), lane0 arrival add. Consumer wave polls the one u64 pair
// covering its 2 producer cohorts. ONE __syncthreads/step (Gs double-buffered).
__global__ __launch_bounds__(256, 1) void k_scan(
    const float* __restrict__ x,
    const unsigned short* __restrict__ wp,
    const float* __restrict__ bias,
    float* __restrict__ out,
    unsigned* __restrict__ done,
    unsigned short* __restrict__ hring) {
  __shared__ __align__(16) unsigned short Wlds[32 * W_STR];   // 98816 B
  __shared__ float Gs[2][4][32 * G_STR];                      // 36864 B

  const int tid = threadIdx.x;
  const int lane = tid & 63;
  const int ks = tid >> 6;          // wave = K-slice
  const int bid = blockIdx.x;
  const int g = bid & 1;            // batch group (rows g*32..g*32+31)
  const int cb = bid >> 1;          // col-block (units cb*8..cb*8+7)
  const int cohort = cb >> 4;       // 8 cohorts of 16 blocks
  const int n = lane & 31;          // MFMA row/col index within tile
  const int hh = lane >> 5;         // k-half selector

  // one-time: weights -> LDS (32 local cols x 1536 K)
  for (int i = tid; i < 32 * 192; i += 256) {
    int row = i / 192, o = i % 192;
    *(short8*)&Wlds[row * W_STR + o * 8] =
        *(const short8*)&wp[((size_t)cb * 32 + row) * 1536 + o * 8];
  }

  const int m = tid >> 3, uu = tid & 7;   // gate-math thread = (batch row m, unit uu)
  const int ug = cb * 8 + uu;
  const float bi = bias[ug], bff = bias[1024 + ug];
  const float bc_ = bias[2048 + ug], bo = bias[3072 + ug];
  float c_state = 0.f;
  __syncthreads();

  const unsigned short* wb = &Wlds[n * W_STR + hh * 8];

  #pragma unroll 1
  for (int t = 0; t < T_STEPS; ++t) {
    f32x16 acc;
    #pragma unroll
    for (int r = 0; r < 16; ++r) acc[r] = 0.f;

    // ---- X phase: direct f32 loads + cvt, no h dependency (overlaps producer slack) ----
    {
      const float* xs = x + ((size_t)(g * 32 + n) * 512 + t) * 512 + ks * 128 + hh * 8;
      #pragma unroll
      for (int kk = 0; kk < 8; ++kk) {
        float4 a0 = *(const float4*)(xs + kk * 16);
        float4 a1 = *(const float4*)(xs + kk * 16 + 4);
        short8 xa;
        xa[0] = (short)f2bf(a0.x); xa[1] = (short)f2bf(a0.y);
        xa[2] = (short)f2bf(a0.z); xa[3] = (short)f2bf(a0.w);
        xa[4] = (short)f2bf(a1.x); xa[5] = (short)f2bf(a1.y);
        xa[6] = (short)f2bf(a1.z); xa[7] = (short)f2bf(a1.w);
        short8 b = *(const short8*)(wb + ks * 128 + kk * 16);
        acc = __builtin_amdgcn_mfma_f32_32x32x16_bf16(xa, b, acc, 0, 0, 0);
      }
    }

    // ---- per-wave wake: lane0 polls ONE u64 pair-line (cohorts 2ks, 2ks+1) ----
    if (t > 0 && lane == 0) {
      const unsigned long long* dp = (const unsigned long long*)(
          done + (((size_t)(t - 1) * 2 + g) * 4 + ks) * 16);
      while (__hip_atomic_load(dp, __ATOMIC_RELAXED,
                               __HIP_MEMORY_SCOPE_AGENT) != 0x0000004000000040ULL)
        __builtin_amdgcn_s_sleep(1);
    }
    // compiler ordering guard: h loads below must not hoist above the spin
    __builtin_amdgcn_fence(__ATOMIC_ACQUIRE, "workgroup");
    // windowed invalidate: stale ring lines are >=16 steps old
    if (t > 0 && (t & (RING - 1)) == 0)
      __builtin_amdgcn_fence(__ATOMIC_ACQUIRE, "agent");

    // ---- H phase: direct global->VGPR A-frags (L2-cached, LLC-backed), LDS weights ----
    {
      const unsigned short* hs = hring + (size_t)(t & (RING - 1)) * SLOT_SHORTS +
                                 (size_t)(g * 32 + n) * 1024 + ks * 256 + hh * 8;
      short8 ha[16];
      #pragma unroll
      for (int kk = 0; kk < 16; ++kk)
        ha[kk] = *(const short8*)(hs + kk * 16);
      #pragma unroll
      for (int kk = 0; kk < 16; ++kk) {
        short8 b = *(const short8*)(wb + 512 + ks * 256 + kk * 16);
        acc = __builtin_amdgcn_mfma_f32_32x32x16_bf16(ha[kk], b, acc, 0, 0, 0);
      }
    }

    // ---- partials to double-buffered LDS (32x32 C/D: col=n, row=(r&3)+8*(r>>2)+4*hh) ----
    #pragma unroll
    for (int r = 0; r < 16; ++r) {
      int row = (r & 3) + 8 * (r >> 2) + 4 * hh;
      Gs[t & 1][ks][row * G_STR + n] = acc[r];
    }
    __syncthreads();   // the ONLY barrier: partial-write -> gate-read

    // ---- gate math: wave w's threads cover exactly rows w*8..w*8+7 ----
    float sI = bi, sF = bff, sC = bc_, sO = bo;
    #pragma unroll
    for (int w = 0; w < 4; ++w) {
      sI += Gs[t & 1][w][m * G_STR + uu];
      sF += Gs[t & 1][w][m * G_STR + 8 + uu];
      sC += Gs[t & 1][w][m * G_STR + 16 + uu];
      sO += Gs[t & 1][w][m * G_STR + 24 + uu];
    }
    float ig = 1.f / (1.f + __expf(-sI));
    float fg = 1.f / (1.f + __expf(-sF));
    float og = 1.f / (1.f + __expf(-sO));
    float cb2 = tanhf(sC);
    c_state = fg * c_state + ig * cb2;
    float h = og * tanhf(c_state);

    // pack 4 units -> 8B AGENT-scope atomic store (stops at LLC; no HBM RMW)
    unsigned hv = (unsigned)f2bf(h);
    unsigned o1 = (unsigned)__shfl_xor((int)hv, 1, 64);
    unsigned lo = hv | (o1 << 16);
    unsigned long long hi = (unsigned long long)(unsigned)__shfl_xor((int)lo, 2, 64);
    unsigned long long v64 = ((unsigned long long)lo) | (hi << 32);
    if ((uu & 3) == 0) {
      unsigned short* hdst = hring + (size_t)((t + 1) & (RING - 1)) * SLOT_SHORTS;
      __hip_atomic_store(
          (unsigned long long*)(hdst + (size_t)(g * 32 + m) * 1024 + cb * 8 + uu),
          v64, __ATOMIC_RELAXED, __HIP_MEMORY_SCOPE_AGENT);
    }
    if (t == T_STEPS - 1) {
      float* orow = out + (size_t)(g * 32 + m) * 3072 + ug;
      orow[0] = h;
      orow[1024] = h;
      orow[2048] = c_state;
    }
    // per-WAVE drain: this wave's h stores ACKed at LLC, then fire-and-forget arrival
    asm volatile("s_waitcnt vmcnt(0)" ::: "memory");
    if (lane == 0)
      __hip_atomic_fetch_add(
          done + (((size_t)t * 2 + g) * 4 + (cohort >> 1)) * 16 + (cohort & 1),
          1u, __ATOMIC_RELAXED, __HIP_MEMORY_SCOPE_AGENT);
  }
}

extern "C" void kernel_launch(void* const* d_in, const int* in_sizes, int n_in,
                              void* d_out, int out_size, void* d_ws, size_t ws_size,
                              hipStream_t stream) {
  const float* x  = (const float*)d_in[0];
  const float* Wx = (const float*)d_in[1];
  const float* Wh = (const float*)d_in[2];
  const float* b  = (const float*)d_in[3];
  float* out = (float*)d_out;
  char* ws = (char*)d_ws;
  unsigned* done = (unsigned*)(ws + OFF_DONE);
  unsigned short* hring = (unsigned short*)(ws + OFF_HRING);
  unsigned short* wp = (unsigned short*)(ws + OFF_WPACK);

  hipMemsetAsync(d_ws, 0, MEMSET_BYTES, stream);
  k_wpack<<<1536, 256, 0, stream>>>(Wx, Wh, wp);

  void* args[] = {(void*)&x, (void*)&wp, (void*)&b, (void*)&out, (void*)&done,
                  (void*)&hring};
  hipLaunchCooperativeKernel((void*)k_scan, dim3(256), dim3(256), args, 0, stream);
}

// Round 8
// 2969.380 us; speedup vs baseline: 1.2493x; 1.2493x over previous
//
#include <hip/hip_runtime.h>
#include <stdint.h>

#define T_STEPS 512
#define RING 128
#define SLOT_SHORTS (64 * 1024)   // one h slot: 64x1024 bf16 = 128 KB

typedef short short8 __attribute__((ext_vector_type(8)));
typedef float f32x16 __attribute__((ext_vector_type(16)));

// ---- ws layout (bytes) ----
// done: [512][2 groups][4 pair-lines] x 64B; pair-line k = u64 {cnt[2k],cnt[2k+1]},
// counting BLOCKS: 16 per cohort.
#define OFF_DONE 0
#define DONE_BYTES (512 * 2 * 4 * 64)               // 256 KB
#define OFF_HRING DONE_BYTES                        // 128 slots x 128 KB = 16 MB
#define OFF_WPACK (OFF_HRING + RING * SLOT_SHORTS * 2)
#define MEMSET_BYTES (OFF_HRING + SLOT_SHORTS * 2)  // counters + ring slot 0 (h_{-1}=0)

// LDS strides
#define W_STR 1544   // shorts = 772 dw
#define G_STR 36     // floats

__device__ __forceinline__ unsigned short f2bf(float f) {
  unsigned u = __float_as_uint(f);
  u += 0x7fffu + ((u >> 16) & 1u);   // RNE
  return (unsigned short)(u >> 16);
}

// ---- prep: W [k][col] f32 -> wp [colpack][k] bf16 ----
// col = g*1024 + u  ->  cp = (u>>3)*32 + g*8 + (u&7)  (block cb owns cp rows cb*32..+31)
__global__ __launch_bounds__(256) void k_wpack(const float* __restrict__ Wx,
                                               const float* __restrict__ Wh,
                                               unsigned short* __restrict__ wp) {
  __shared__ unsigned short tile[64 * 68];
  int tid = threadIdx.x, lane = tid & 63, wave = tid >> 6;
  int kt = blockIdx.x >> 6;   // 0..23
  int ct = blockIdx.x & 63;   // 0..63
  int K0 = kt * 64, C0 = ct * 64;
  const float* src = (K0 < 512) ? (Wx + (size_t)K0 * 4096)
                                : (Wh + (size_t)(K0 - 512) * 4096);
  #pragma unroll
  for (int i = 0; i < 16; ++i) {
    int kl = i * 4 + wave;
    float v = src[(size_t)kl * 4096 + C0 + lane];
    tile[lane * 68 + kl] = f2bf(v);
  }
  __syncthreads();
  #pragma unroll
  for (int i = 0; i < 16; ++i) {
    int c = i * 4 + wave;
    int col = C0 + c;
    int gg = col >> 10, idx = col & 1023;
    int cp = (idx >> 3) * 32 + gg * 8 + (idx & 7);
    wp[(size_t)cp * 1536 + K0 + lane] = tile[c * 68 + lane];
  }
}

// ---- persistent scan ----
// 256 blocks x 256 threads. g = bid&1 (32 batch rows), cb = bid>>1 (8 units = 32 cols).
// Wave = K-slice ks: X K [ks*128,+128), H K [ks*256,+256). 32x32x16 MFMA.
// R6-proven sync skeleton (block arrival, 16/cohort, u64-pair poll, 2 barriers).
// R8: burn-poll (DVFS discriminator) + RING=128 (4 window fences instead of 32).
__global__ __launch_bounds__(256, 1) void k_scan(
    const float* __restrict__ x,
    const unsigned short* __restrict__ wp,
    const float* __restrict__ bias,
    float* __restrict__ out,
    unsigned* __restrict__ done,
    unsigned short* __restrict__ hring) {
  __shared__ __align__(16) unsigned short Wlds[32 * W_STR];   // 98816 B
  __shared__ float Gs[4][32 * G_STR];                         // 18432 B

  const int tid = threadIdx.x;
  const int lane = tid & 63;
  const int ks = tid >> 6;          // wave = K-slice
  const int bid = blockIdx.x;
  const int g = bid & 1;            // batch group (rows g*32..g*32+31)
  const int cb = bid >> 1;          // col-block (units cb*8..cb*8+7)
  const int cohort = cb >> 4;       // 8 cohorts of 16 blocks
  const int n = lane & 31;          // MFMA row/col index within tile
  const int hh = lane >> 5;         // k-half selector

  // one-time: weights -> LDS (32 local cols x 1536 K)
  for (int i = tid; i < 32 * 192; i += 256) {
    int row = i / 192, o = i % 192;
    *(short8*)&Wlds[row * W_STR + o * 8] =
        *(const short8*)&wp[((size_t)cb * 32 + row) * 1536 + o * 8];
  }

  const int m = tid >> 3, uu = tid & 7;   // gate-math thread = (batch row m, unit uu)
  const int ug = cb * 8 + uu;
  const float bi = bias[ug], bff = bias[1024 + ug];
  const float bc_ = bias[2048 + ug], bo = bias[3072 + ug];
  float c_state = 0.f;
  __syncthreads();

  const unsigned short* wb = &Wlds[n * W_STR + hh * 8];

  #pragma unroll 1
  for (int t = 0; t < T_STEPS; ++t) {
    f32x16 acc;
    #pragma unroll
    for (int r = 0; r < 16; ++r) acc[r] = 0.f;

    // ---- X phase: direct f32 loads + cvt, no h dependency ----
    {
      const float* xs = x + ((size_t)(g * 32 + n) * 512 + t) * 512 + ks * 128 + hh * 8;
      #pragma unroll
      for (int kk = 0; kk < 8; ++kk) {
        float4 a0 = *(const float4*)(xs + kk * 16);
        float4 a1 = *(const float4*)(xs + kk * 16 + 4);
        short8 xa;
        xa[0] = (short)f2bf(a0.x); xa[1] = (short)f2bf(a0.y);
        xa[2] = (short)f2bf(a0.z); xa[3] = (short)f2bf(a0.w);
        xa[4] = (short)f2bf(a1.x); xa[5] = (short)f2bf(a1.y);
        xa[6] = (short)f2bf(a1.z); xa[7] = (short)f2bf(a1.w);
        short8 b = *(const short8*)(wb + ks * 128 + kk * 16);
        acc = __builtin_amdgcn_mfma_f32_32x32x16_bf16(xa, b, acc, 0, 0, 0);
      }
    }

    // ---- per-wave wake: lane0 BURN-polls its u64 pair-line (cohorts 2ks, 2ks+1) ----
    // Dependent-FMA burn keeps the SIMD issuing so the kernel looks busy to the
    // DVFS governor (R7 post-mortem: all structures floor at ~3 ms with pipes
    // <9% busy — consistent with a low DPM state; this round discriminates).
    if (t > 0 && lane == 0) {
      const unsigned long long* dp = (const unsigned long long*)(
          done + (((size_t)(t - 1) * 2 + g) * 4 + ks) * 16);
      float burn = c_state + 1.0f;
      while (__hip_atomic_load(dp, __ATOMIC_RELAXED,
                               __HIP_MEMORY_SCOPE_AGENT) != 0x0000001000000010ULL) {
        #pragma unroll
        for (int i = 0; i < 64; ++i)
          burn = __builtin_fmaf(burn, 1.0000001f, 1e-30f);
      }
      asm volatile("" :: "v"(burn));   // keep the burn alive
    }
    // compiler ordering guard: h loads below must not hoist above the spin
    __builtin_amdgcn_fence(__ATOMIC_ACQUIRE, "workgroup");
    // windowed invalidate: stale ring lines are >=128 steps old (4 fences total)
    if (t > 0 && (t & (RING - 1)) == 0)
      __builtin_amdgcn_fence(__ATOMIC_ACQUIRE, "agent");

    // ---- H phase: direct global->VGPR A-frags, MFMA against LDS weights ----
    {
      const unsigned short* hs = hring + (size_t)(t & (RING - 1)) * SLOT_SHORTS +
                                 (size_t)(g * 32 + n) * 1024 + ks * 256 + hh * 8;
      short8 ha[16];
      #pragma unroll
      for (int kk = 0; kk < 16; ++kk)
        ha[kk] = *(const short8*)(hs + kk * 16);
      #pragma unroll
      for (int kk = 0; kk < 16; ++kk) {
        short8 b = *(const short8*)(wb + 512 + ks * 256 + kk * 16);
        acc = __builtin_amdgcn_mfma_f32_32x32x16_bf16(ha[kk], b, acc, 0, 0, 0);
      }
    }

    // ---- partials to LDS (32x32 C/D: col=lane&31, row=(r&3)+8*(r>>2)+4*(lane>>5)) ----
    #pragma unroll
    for (int r = 0; r < 16; ++r) {
      int row = (r & 3) + 8 * (r >> 2) + 4 * hh;
      Gs[ks][row * G_STR + n] = acc[r];
    }
    __syncthreads();

    // ---- gate math: all 256 threads, (m, uu); sum 4 K-slice partials ----
    float sI = bi, sF = bff, sC = bc_, sO = bo;
    #pragma unroll
    for (int w = 0; w < 4; ++w) {
      sI += Gs[w][m * G_STR + uu];
      sF += Gs[w][m * G_STR + 8 + uu];
      sC += Gs[w][m * G_STR + 16 + uu];
      sO += Gs[w][m * G_STR + 24 + uu];
    }
    float ig = 1.f / (1.f + __expf(-sI));
    float fg = 1.f / (1.f + __expf(-sF));
    float og = 1.f / (1.f + __expf(-sO));
    float cb2 = tanhf(sC);
    c_state = fg * c_state + ig * cb2;
    float h = og * tanhf(c_state);

    // pack 4 units -> 8B write-through store to LLC ring
    unsigned hv = (unsigned)f2bf(h);
    unsigned o1 = (unsigned)__shfl_xor((int)hv, 1, 64);
    unsigned lo = hv | (o1 << 16);
    unsigned long long hi = (unsigned long long)(unsigned)__shfl_xor((int)lo, 2, 64);
    unsigned long long v64 = ((unsigned long long)lo) | (hi << 32);
    if ((uu & 3) == 0) {
      unsigned short* hdst = hring + (size_t)((t + 1) & (RING - 1)) * SLOT_SHORTS;
      __hip_atomic_store(
          (unsigned long long*)(hdst + (size_t)(g * 32 + m) * 1024 + cb * 8 + uu),
          v64, __ATOMIC_RELAXED, __HIP_MEMORY_SCOPE_SYSTEM);
    }
    if (t == T_STEPS - 1) {
      float* orow = out + (size_t)(g * 32 + m) * 3072 + ug;
      orow[0] = h;
      orow[1024] = h;
      orow[2048] = c_state;
    }
    __syncthreads();   // per-wave vmcnt(0) drain: all h stores ACKed at LLC
    if (tid == 0)
      __hip_atomic_fetch_add(
          done + (((size_t)t * 2 + g) * 4 + (cohort >> 1)) * 16 + (cohort & 1),
          1u, __ATOMIC_RELAXED, __HIP_MEMORY_SCOPE_AGENT);
  }
}

extern "C" void kernel_launch(void* const* d_in, const int* in_sizes, int n_in,
                              void* d_out, int out_size, void* d_ws, size_t ws_size,
                              hipStream_t stream) {
  const float* x  = (const float*)d_in[0];
  const float* Wx = (const float*)d_in[1];
  const float* Wh = (const float*)d_in[2];
  const float* b  = (const float*)d_in[3];
  float* out = (float*)d_out;
  char* ws = (char*)d_ws;
  unsigned* done = (unsigned*)(ws + OFF_DONE);
  unsigned short* hring = (unsigned short*)(ws + OFF_HRING);
  unsigned short* wp = (unsigned short*)(ws + OFF_WPACK);

  hipMemsetAsync(d_ws, 0, MEMSET_BYTES, stream);
  k_wpack<<<1536, 256, 0, stream>>>(Wx, Wh, wp);

  void* args[] = {(void*)&x, (void*)&wp, (void*)&b, (void*)&out, (void*)&done,
                  (void*)&hring};
  hipLaunchCooperativeKernel((void*)k_scan, dim3(256), dim3(256), args, 0, stream);
}

// Round 9
// 2301.043 us; speedup vs baseline: 1.6122x; 1.2904x over previous
//
#include <hip/hip_runtime.h>
#include <stdint.h>

#define T_STEPS 512
#define RING 16
#define SLOT_SHORTS 65536   // one h slot: [2 g][4 ks][16 kk][64 lane][8] bf16 = 128 KB

typedef short short8 __attribute__((ext_vector_type(8)));
typedef float f32x16 __attribute__((ext_vector_type(16)));

// ---- ws layout (bytes) ----
// done: [512][2 groups][4 pair-lines] x 64B; pair-line k = u64 {cnt[2k],cnt[2k+1]},
// counting BLOCKS: 16 per cohort.
#define OFF_DONE 0
#define DONE_BYTES (512 * 2 * 4 * 64)               // 256 KB
#define OFF_HRING DONE_BYTES                        // 16 slots x 128 KB = 2 MB
#define OFF_XF (OFF_HRING + RING * SLOT_SHORTS * 2) // x in A-frag order, 32 MB
#define XF_BYTES (512 * 2 * 4 * 8 * 64 * 8 * 2)
#define OFF_WPACK (OFF_XF + XF_BYTES)               // [4096][1536] bf16 = 12 MB
#define MEMSET_BYTES (OFF_HRING + SLOT_SHORTS * 2)  // counters + ring slot 0 (h_{-1}=0)

// LDS strides
#define W_STR 1544   // shorts = 772 dw
#define G_STR 36     // floats

__device__ __forceinline__ unsigned short f2bf(float f) {
  unsigned u = __float_as_uint(f);
  u += 0x7fffu + ((u >> 16) & 1u);   // RNE
  return (unsigned short)(u >> 16);
}

// ---- prep: x [B][T][D] f32 -> xf [t][g][ks][kk][lane=hh*32+n][8] bf16 ----
// A-fragment order: one-shot transform so the scan's X loads are 16B/lane coalesced.
__global__ __launch_bounds__(256) void k_xpack(const float* __restrict__ x,
                                               unsigned short* __restrict__ xf) {
  int o = blockIdx.x * 256 + threadIdx.x;   // 2,097,152 vec8 cells
  int lane = o & 63;
  int kk = (o >> 6) & 7;
  int ks = (o >> 9) & 3;
  int g = (o >> 11) & 1;
  int t = o >> 12;
  int n = lane & 31, hh = lane >> 5;
  const float* src = x + (((size_t)(g * 32 + n) * 512 + t) * 512 +
                          ks * 128 + kk * 16 + hh * 8);
  float4 v0 = *(const float4*)src;
  float4 v1 = *(const float4*)(src + 4);
  short8 w;
  w[0] = (short)f2bf(v0.x); w[1] = (short)f2bf(v0.y);
  w[2] = (short)f2bf(v0.z); w[3] = (short)f2bf(v0.w);
  w[4] = (short)f2bf(v1.x); w[5] = (short)f2bf(v1.y);
  w[6] = (short)f2bf(v1.z); w[7] = (short)f2bf(v1.w);
  *(short8*)(xf + (size_t)o * 8) = w;
}

// ---- prep: W [k][col] f32 -> wp [colpack][k] bf16 ----
// col = g*1024 + u  ->  cp = (u>>3)*32 + g*8 + (u&7)  (block cb owns cp rows cb*32..+31)
__global__ __launch_bounds__(256) void k_wpack(const float* __restrict__ Wx,
                                               const float* __restrict__ Wh,
                                               unsigned short* __restrict__ wp) {
  __shared__ unsigned short tile[64 * 68];
  int tid = threadIdx.x, lane = tid & 63, wave = tid >> 6;
  int kt = blockIdx.x >> 6;   // 0..23
  int ct = blockIdx.x & 63;   // 0..63
  int K0 = kt * 64, C0 = ct * 64;
  const float* src = (K0 < 512) ? (Wx + (size_t)K0 * 4096)
                                : (Wh + (size_t)(K0 - 512) * 4096);
  #pragma unroll
  for (int i = 0; i < 16; ++i) {
    int kl = i * 4 + wave;
    float v = src[(size_t)kl * 4096 + C0 + lane];
    tile[lane * 68 + kl] = f2bf(v);
  }
  __syncthreads();
  #pragma unroll
  for (int i = 0; i < 16; ++i) {
    int c = i * 4 + wave;
    int col = C0 + c;
    int gg = col >> 10, idx = col & 1023;
    int cp = (idx >> 3) * 32 + gg * 8 + (idx & 7);
    wp[(size_t)cp * 1536 + K0 + lane] = tile[c * 68 + lane];
  }
}

// ---- persistent scan ----
// 256 blocks x 256 threads. g = bid&1 (32 batch rows), cb = bid>>1 (8 units = 32 cols).
// Wave = K-slice ks: X K [ks*128,+128), H K [ks*256,+256). 32x32x16 MFMA.
// R9: BOTH A-operand streams in fragment order -> all global loads 16B/lane
// coalesced (R8 post-mortem: row-per-lane loads = 64 lines/instr, ~8k VMEM
// transactions/CU/step was the floor). h produced directly in fragment order:
// block cb's 8 units = exactly one (ks,kk,hh) cell; 512B contiguous store.
__global__ __launch_bounds__(256, 1) void k_scan(
    const unsigned short* __restrict__ xf,
    const unsigned short* __restrict__ wp,
    const float* __restrict__ bias,
    float* __restrict__ out,
    unsigned* __restrict__ done,
    unsigned short* __restrict__ hring) {
  __shared__ __align__(16) unsigned short Wlds[32 * W_STR];   // 98816 B
  __shared__ float Gs[4][32 * G_STR];                         // 18432 B

  const int tid = threadIdx.x;
  const int lane = tid & 63;
  const int ks = tid >> 6;          // wave = K-slice
  const int bid = blockIdx.x;
  const int g = bid & 1;            // batch group (rows g*32..g*32+31)
  const int cb = bid >> 1;          // col-block (units cb*8..cb*8+7)
  const int cohort = cb >> 4;       // 8 cohorts of 16 blocks
  const int n = lane & 31;          // MFMA row/col index within tile
  const int hh = lane >> 5;         // k-half selector

  // one-time: weights -> LDS (32 local cols x 1536 K)
  for (int i = tid; i < 32 * 192; i += 256) {
    int row = i / 192, o = i % 192;
    *(short8*)&Wlds[row * W_STR + o * 8] =
        *(const short8*)&wp[((size_t)cb * 32 + row) * 1536 + o * 8];
  }

  const int m = tid >> 3, uu = tid & 7;   // gate-math thread = (batch row m, unit uu)
  const int ug = cb * 8 + uu;
  const float bi = bias[ug], bff = bias[1024 + ug];
  const float bc_ = bias[2048 + ug], bo = bias[3072 + ug];
  float c_state = 0.f;
  // producer fragment cell for this block's 8 units:
  const int ksp = cb >> 5, kkp = (cb >> 1) & 15, hhp = cb & 1;
  __syncthreads();

  const unsigned short* wb = &Wlds[n * W_STR + hh * 8];

  #pragma unroll 1
  for (int t = 0; t < T_STEPS; ++t) {
    f32x16 acc;
    #pragma unroll
    for (int r = 0; r < 16; ++r) acc[r] = 0.f;

    // ---- X phase: coalesced fragment loads (16B/lane), no h dependency ----
    {
      const unsigned short* xs =
          xf + ((((size_t)t * 2 + g) * 4 + ks) * 8) * 512 + lane * 8;
      #pragma unroll
      for (int kk = 0; kk < 8; ++kk) {
        short8 xa = *(const short8*)(xs + kk * 512);
        short8 b = *(const short8*)(wb + ks * 128 + kk * 16);
        acc = __builtin_amdgcn_mfma_f32_32x32x16_bf16(xa, b, acc, 0, 0, 0);
      }
    }

    // ---- per-wave wake: lane0 burn-polls its u64 pair-line (cohorts 2ks, 2ks+1) ----
    if (t > 0 && lane == 0) {
      const unsigned long long* dp = (const unsigned long long*)(
          done + (((size_t)(t - 1) * 2 + g) * 4 + ks) * 16);
      float burn = c_state + 1.0f;
      while (__hip_atomic_load(dp, __ATOMIC_RELAXED,
                               __HIP_MEMORY_SCOPE_AGENT) != 0x0000001000000010ULL) {
        #pragma unroll
        for (int i = 0; i < 64; ++i)
          burn = __builtin_fmaf(burn, 1.0000001f, 1e-30f);
      }
      asm volatile("" :: "v"(burn));
    }
    // compiler ordering guard: h loads below must not hoist above the spin
    __builtin_amdgcn_fence(__ATOMIC_ACQUIRE, "workgroup");
    // windowed invalidate: stale ring lines are >=16 steps old
    if (t > 0 && (t & (RING - 1)) == 0)
      __builtin_amdgcn_fence(__ATOMIC_ACQUIRE, "agent");

    // ---- H phase: coalesced fragment loads (16B/lane), MFMA vs LDS weights ----
    {
      const unsigned short* hs = hring + (size_t)(t & (RING - 1)) * SLOT_SHORTS +
                                 ((g * 4 + ks) * 16) * 512 + lane * 8;
      short8 ha[16];
      #pragma unroll
      for (int kk = 0; kk < 16; ++kk)
        ha[kk] = *(const short8*)(hs + kk * 512);
      #pragma unroll
      for (int kk = 0; kk < 16; ++kk) {
        short8 b = *(const short8*)(wb + 512 + ks * 256 + kk * 16);
        acc = __builtin_amdgcn_mfma_f32_32x32x16_bf16(ha[kk], b, acc, 0, 0, 0);
      }
    }

    // ---- partials to LDS (32x32 C/D: col=lane&31, row=(r&3)+8*(r>>2)+4*(lane>>5)) ----
    #pragma unroll
    for (int r = 0; r < 16; ++r) {
      int row = (r & 3) + 8 * (r >> 2) + 4 * hh;
      Gs[ks][row * G_STR + n] = acc[r];
    }
    __syncthreads();

    // ---- gate math: all 256 threads, (m, uu); sum 4 K-slice partials ----
    float sI = bi, sF = bff, sC = bc_, sO = bo;
    #pragma unroll
    for (int w = 0; w < 4; ++w) {
      sI += Gs[w][m * G_STR + uu];
      sF += Gs[w][m * G_STR + 8 + uu];
      sC += Gs[w][m * G_STR + 16 + uu];
      sO += Gs[w][m * G_STR + 24 + uu];
    }
    float ig = 1.f / (1.f + __expf(-sI));
    float fg = 1.f / (1.f + __expf(-sF));
    float og = 1.f / (1.f + __expf(-sO));
    float cb2 = tanhf(sC);
    c_state = fg * c_state + ig * cb2;
    float h = og * tanhf(c_state);

    // pack 4 units -> 8B agent-scope store into the NEXT slot's fragment cell
    unsigned hv = (unsigned)f2bf(h);
    unsigned o1 = (unsigned)__shfl_xor((int)hv, 1, 64);
    unsigned lo = hv | (o1 << 16);
    unsigned long long hi = (unsigned long long)(unsigned)__shfl_xor((int)lo, 2, 64);
    unsigned long long v64 = ((unsigned long long)lo) | (hi << 32);
    if ((uu & 3) == 0) {
      unsigned short* hdst = hring + (size_t)((t + 1) & (RING - 1)) * SLOT_SHORTS +
                             ((g * 4 + ksp) * 16 + kkp) * 512 +
                             (hhp * 32 + m) * 8 + uu;
      __hip_atomic_store((unsigned long long*)hdst, v64,
                         __ATOMIC_RELAXED, __HIP_MEMORY_SCOPE_AGENT);
    }
    if (t == T_STEPS - 1) {
      float* orow = out + (size_t)(g * 32 + m) * 3072 + ug;
      orow[0] = h;
      orow[1024] = h;
      orow[2048] = c_state;
    }
    __syncthreads();   // per-wave vmcnt(0) drain: all h stores ACKed at LLC
    if (tid == 0)
      __hip_atomic_fetch_add(
          done + (((size_t)t * 2 + g) * 4 + (cohort >> 1)) * 16 + (cohort & 1),
          1u, __ATOMIC_RELAXED, __HIP_MEMORY_SCOPE_AGENT);
  }
}

extern "C" void kernel_launch(void* const* d_in, const int* in_sizes, int n_in,
                              void* d_out, int out_size, void* d_ws, size_t ws_size,
                              hipStream_t stream) {
  const float* x  = (const float*)d_in[0];
  const float* Wx = (const float*)d_in[1];
  const float* Wh = (const float*)d_in[2];
  const float* b  = (const float*)d_in[3];
  float* out = (float*)d_out;
  char* ws = (char*)d_ws;
  unsigned* done = (unsigned*)(ws + OFF_DONE);
  unsigned short* hring = (unsigned short*)(ws + OFF_HRING);
  unsigned short* xf = (unsigned short*)(ws + OFF_XF);
  unsigned short* wp = (unsigned short*)(ws + OFF_WPACK);

  hipMemsetAsync(d_ws, 0, MEMSET_BYTES, stream);
  k_xpack<<<8192, 256, 0, stream>>>(x, xf);
  k_wpack<<<1536, 256, 0, stream>>>(Wx, Wh, wp);

  void* args[] = {(void*)&xf, (void*)&wp, (void*)&b, (void*)&out, (void*)&done,
                  (void*)&hring};
  hipLaunchCooperativeKernel((void*)k_scan, dim3(256), dim3(256), args, 0, stream);
}